// Round 10
// baseline (647.612 us; speedup 1.0000x reference)
//
#include <hip/hip_runtime.h>
#include <math.h>

#define B 256
#define D 512
#define S 196
#define SQ 49    // float4 quads per 196-float row
#define NCH 8    // row-chunks of 64

// ---------------- K1: gpart[(b*8+ce)*D + d] = sum_{e in chunk ce} u[b,e]*W[e,d]
// u = ctrl*w_attn. Grid 256 (ce x b-octet) x 256 thr; W row loaded once,
// reused for 8 batches from registers (W L2 traffic 32 MB). Block 0 also
// zeroes the arrival counters (ws is re-poisoned 0xAA before every call).
__global__ __launch_bounds__(256) void k_gemm(const float* __restrict__ ctrl,
                                              const float* __restrict__ w_attn,
                                              const float* __restrict__ W,
                                              float* __restrict__ gpart,
                                              int* __restrict__ cnt) {
    __shared__ float u_s[64][8];
    const int ce = blockIdx.x >> 5;
    const int b0 = (blockIdx.x & 31) * 8;
    const int t = threadIdx.x;
    if (blockIdx.x == 0) cnt[t] = 0;     // B == 256 == blockDim
#pragma unroll
    for (int k = t; k < 512; k += 256) {
        const int j = k & 7, el = k >> 3;
        const int e = ce * 64 + el;
        u_s[el][j] = ctrl[(b0 + j) * D + e] * w_attn[e];
    }
    __syncthreads();
    float a0[8], a1[8];
#pragma unroll
    for (int j = 0; j < 8; ++j) { a0[j] = 0.f; a1[j] = 0.f; }
    for (int e0 = 0; e0 < 64; e0 += 4) {
        float w0[4], w1[4];
#pragma unroll
        for (int i = 0; i < 4; ++i) {
            const int e = ce * 64 + e0 + i;
            w0[i] = W[e * D + t];
            w1[i] = W[e * D + t + 256];
        }
#pragma unroll
        for (int i = 0; i < 4; ++i) {
            const float4 ua = *(const float4*)&u_s[e0 + i][0];
            const float4 ub = *(const float4*)&u_s[e0 + i][4];
            a0[0] += ua.x * w0[i]; a0[1] += ua.y * w0[i];
            a0[2] += ua.z * w0[i]; a0[3] += ua.w * w0[i];
            a0[4] += ub.x * w0[i]; a0[5] += ub.y * w0[i];
            a0[6] += ub.z * w0[i]; a0[7] += ub.w * w0[i];
            a1[0] += ua.x * w1[i]; a1[1] += ua.y * w1[i];
            a1[2] += ua.z * w1[i]; a1[3] += ua.w * w1[i];
            a1[4] += ub.x * w1[i]; a1[5] += ub.y * w1[i];
            a1[6] += ub.z * w1[i]; a1[7] += ub.w * w1[i];
        }
    }
#pragma unroll
    for (int j = 0; j < 8; ++j) {
        gpart[((size_t)(b0 + j) * NCH + ce) * D + t]       = a0[j];
        gpart[((size_t)(b0 + j) * NCH + ce) * D + t + 256] = a1[j];
    }
}

// ---------------- K2: p-head + partial logits + last-block softmax/wsum.
// Grid B*8 = 2048 x 256 thr. Each block: p-slice from gpart, logits over its
// 64-row chunk (one coalesced 784B row per wave-instruction), rai partial ->
// ws, then __threadfence + atomicAdd(cnt[b]). The 8th arriver for batch b
// (device-scope atomics, G12; fences for cross-XCD visibility, G16) runs the
// softmax from the 8 partials and the weighted sum over all 512 rows of
// kb[b] (L3-hot, 400 KB) -- overlapping early batches' wsum with late
// batches' logits and removing the k_wsum launch + redundant softmax heads.
__global__ __launch_bounds__(256) void k_logits_fin(const float* __restrict__ kb,
                                                    const float* __restrict__ gpart,
                                                    const float* __restrict__ mem,
                                                    const float* __restrict__ ctrl,
                                                    const float* __restrict__ w_attn,
                                                    float* __restrict__ rai_part,
                                                    int* __restrict__ cnt,
                                                    float* __restrict__ out) {
    __shared__ float p_s[64];
    __shared__ float part[4][S];
    __shared__ float rvi_s[S];
    __shared__ float redm[4], reds[4];
    __shared__ int is_last;
    const int bid = blockIdx.x;
    const int b = bid >> 3, c = bid & 7;
    const int t = threadIdx.x;
    const int w = t >> 6, l = t & 63;

    // p-head: p[d] = mem*sum_ce(gpart) + ctrl*w_attn (b_concat dropped:
    // softmax-shift-invariant)
    if (t < 64) {
        const int d = c * 64 + t;
        float s = 0.f;
#pragma unroll
        for (int ce = 0; ce < NCH; ++ce)
            s += gpart[((size_t)b * NCH + ce) * D + d];
        p_s[t] = mem[b * D + d] * s + ctrl[b * D + d] * w_attn[d];
    }
    __syncthreads();

    // partial logits over this chunk's 64 rows
    const float* base = kb + (size_t)b * D * S + (size_t)c * 64 * S;
    if (l < SQ) {
        float4 acc = {0.f, 0.f, 0.f, 0.f};
#pragma unroll
        for (int i = 0; i < 16; ++i) {
            const int r = w * 16 + i;
            const float4 v = *(const float4*)(base + (size_t)r * S + 4 * l);
            const float pv = p_s[r];
            acc.x += pv * v.x; acc.y += pv * v.y;
            acc.z += pv * v.z; acc.w += pv * v.w;
        }
        *(float4*)&part[w][4 * l] = acc;
    }
    __syncthreads();
    if (t < S)
        rai_part[(size_t)bid * S + t] =
            (part[0][t] + part[1][t]) + (part[2][t] + part[3][t]);

    // publish + arrival count (release)
    __threadfence();
    if (t == 0) is_last = (atomicAdd(&cnt[b], 1) == NCH - 1);
    __syncthreads();
    if (!is_last) return;
    __threadfence();   // acquire: invalidate stale cached rai_part lines

    // ---- softmax from the 8 partials of batch b ----
    float rai = -INFINITY;
    if (t < S) {
        float v = 0.f;
#pragma unroll
        for (int k = 0; k < NCH; ++k)
            v += rai_part[((size_t)b * NCH + k) * S + t];
        rai = v;
    }
    float m = rai;
#pragma unroll
    for (int o = 1; o < 64; o <<= 1) m = fmaxf(m, __shfl_xor(m, o, 64));
    if (l == 0) redm[w] = m;
    __syncthreads();
    m = fmaxf(fmaxf(redm[0], redm[1]), fmaxf(redm[2], redm[3]));
    float ex = (t < S) ? __expf(rai - m) : 0.f;
    float sm = ex;
#pragma unroll
    for (int o = 1; o < 64; o <<= 1) sm += __shfl_xor(sm, o, 64);
    if (l == 0) reds[w] = sm;
    __syncthreads();
    const float li = (reds[0] + reds[1]) + (reds[2] + reds[3]);
    if (t < S) rvi_s[t] = ex / li;
    __syncthreads();

    // ---- weighted sum over ALL 512 rows of kb[b] (L3-hot). Wave w: rows
    // w*128..+128 in groups of 4: loads issued before the shuffle-reduces. ----
    float4 rv = {0.f, 0.f, 0.f, 0.f};
    if (l < SQ) rv = *(const float4*)&rvi_s[4 * l];
    const float* kbb = kb + (size_t)b * D * S;
#pragma unroll 1
    for (int i = 0; i < 32; ++i) {
        const int r = w * 128 + i * 4;
        float a0 = 0.f, a1 = 0.f, a2 = 0.f, a3 = 0.f;
        if (l < SQ) {
            const float4 v0 = *(const float4*)(kbb + (size_t)(r    ) * S + 4 * l);
            const float4 v1 = *(const float4*)(kbb + (size_t)(r + 1) * S + 4 * l);
            const float4 v2 = *(const float4*)(kbb + (size_t)(r + 2) * S + 4 * l);
            const float4 v3 = *(const float4*)(kbb + (size_t)(r + 3) * S + 4 * l);
            a0 = rv.x * v0.x + rv.y * v0.y + rv.z * v0.z + rv.w * v0.w;
            a1 = rv.x * v1.x + rv.y * v1.y + rv.z * v1.z + rv.w * v1.w;
            a2 = rv.x * v2.x + rv.y * v2.y + rv.z * v2.z + rv.w * v2.w;
            a3 = rv.x * v3.x + rv.y * v3.y + rv.z * v3.z + rv.w * v3.w;
        }
#pragma unroll
        for (int o = 1; o < 64; o <<= 1) {
            a0 += __shfl_xor(a0, o, 64);
            a1 += __shfl_xor(a1, o, 64);
            a2 += __shfl_xor(a2, o, 64);
            a3 += __shfl_xor(a3, o, 64);
        }
        if (l == 0) {
            float* ob = out + (size_t)b * D + r;
            ob[0] = a0; ob[1] = a1; ob[2] = a2; ob[3] = a3;
        }
    }
}

extern "C" void kernel_launch(void* const* d_in, const int* in_sizes, int n_in,
                              void* d_out, int out_size, void* d_ws, size_t ws_size,
                              hipStream_t stream) {
    const float* mem  = (const float*)d_in[0];  // [B, d]
    const float* ctrl = (const float*)d_in[1];  // [B, d]
    const float* kb   = (const float*)d_in[2];  // [B, d, S]
    const float* W    = (const float*)d_in[3];  // [d, d]
    // d_in[4] = b_concat: softmax-invariant, unused
    const float* wat  = (const float*)d_in[5];  // [d]
    float* out = (float*)d_out;                 // [B, d]

    float* gpart    = (float*)d_ws;                      // B*8*D = 4 MB
    float* rai_part = gpart + (size_t)B * NCH * D;       // 2048*S = 1.6 MB
    int*   cnt      = (int*)(rai_part + (size_t)B * NCH * S);  // B ints

    k_gemm      <<<256,     256, 0, stream>>>(ctrl, wat, W, gpart, cnt);
    k_logits_fin<<<B * NCH, 256, 0, stream>>>(kb, gpart, mem, ctrl, wat,
                                              rai_part, cnt, out);
}